// Round 9
// baseline (117.079 us; speedup 1.0000x reference)
//
#include <hip/hip_runtime.h>
#include <stdint.h>

typedef __attribute__((ext_vector_type(4))) float f32x4;
typedef __attribute__((ext_vector_type(8))) short bf16x8;

#define C_NORM_LOG2E 0.18033688011112043f

// 128B-row swizzle: XOR row&7 (addr bits 7-9) into byte bits 4-6
__device__ __forceinline__ uint32_t swz(uint32_t a) { return a ^ (((a >> 7) & 7u) << 4); }

__device__ __forceinline__ uint32_t cvt_pk_bf16(float a, float b) {
  uint32_t r;
  asm("v_cvt_pk_bf16_f32 %0, %1, %2" : "=v"(r) : "v"(a), "v"(b));
  return r;
}

__device__ __forceinline__ ushort f2bf(float f) {
  uint32_t u = __float_as_uint(f);
  u += 0x7FFFu + ((u >> 16) & 1u);
  return (ushort)(u >> 16);
}

__device__ __forceinline__ void gl_lds16(const void* gp, void* lp) {
  __builtin_amdgcn_global_load_lds((const __attribute__((address_space(1))) void*)gp,
                                   (__attribute__((address_space(3))) void*)lp, 16, 0, 0);
}

// ---------------- projection (+ PEdT pack in trailing blocks) ----------------
// blocks <512: QKV[r][d] bf16, r = (b*16+s)*512 + m, from x[b, 32m+s, :]; W read f32 direct.
// blocks >=512: PEdT[m][n] = PE[2n][2m]*NORM*log2e.
__global__ __launch_bounds__(512, 4) void proj_kernel(
    const float* __restrict__ x, const float* __restrict__ Wk, const float* __restrict__ Wq,
    const float* __restrict__ Wv, const float* __restrict__ PE,
    ushort* __restrict__ Qw, ushort* __restrict__ Kw, ushort* __restrict__ Vw,
    float* __restrict__ PEdT) {
  __shared__ float Xl[2][8192];  // 2 x 32KB: 128 rows x 64 f32, swizzled (256B rows)
  const int tid = threadIdx.x;
  const int bid = blockIdx.x;
  if (bid >= 512) {  // PEdT pack: 512 blocks x 512 threads = 262144 elems
    int i = (bid - 512) * 512 + tid;
    int m = i >> 9, n = i & 511;
    PEdT[i] = PE[n * 2048 + m * 2] * C_NORM_LOG2E;
    return;
  }
  const int lane = tid & 63, w = tid >> 6, g = lane >> 4, l15 = lane & 15;
  const int wr = w >> 2, wc = w & 3;  // 2x4 wave grid: 64 rows x 48 cols each
  const int xcd = bid & 7, idx = bid >> 3;
  const int part = idx & 3, h = idx >> 2;
  const int bs = h * 8 + xcd;          // all 4 parts of segment bs on XCD bs%8
  const int m0 = part * 128;
  const int R0 = bs * 512 + m0;
  const int b = bs >> 4, s = bs & 15;
  const char* xb = (const char*)x + ((size_t)b * 8388608 + (size_t)s * 512) * 4;

  // fixed W rows for this thread's 3 B-fragments (f32, L2/L3-resident)
  const float* wrow[3];
#pragma unroll
  for (int j = 0; j < 3; ++j) {
    int n = wc * 48 + j * 16 + l15;
    wrow[j] = (n < 64) ? Wq + (size_t)n * 512
            : (n < 128) ? Wk + (size_t)(n - 64) * 512
                        : Wv + (size_t)(n - 128) * 512;
  }

  f32x4 acc[4][3];
#pragma unroll
  for (int i = 0; i < 4; ++i)
#pragma unroll
    for (int j = 0; j < 3; ++j) acc[i][j] = (f32x4){0.f, 0.f, 0.f, 0.f};

  auto stage = [&](int kt, int buf) {
#pragma unroll
    for (int j = 0; j < 4; ++j) {
      uint32_t sl = (uint32_t)(j * 8192 + tid * 16);      // linear LDS byte slot
      uint32_t t = sl ^ (((sl >> 8) & 7u) << 4);          // pre-swizzled source index
      uint32_t row = t >> 8, colb = t & 255u;
      const char* src = xb + (size_t)(m0 + row) * 65536 + (size_t)kt * 256 + colb;
      gl_lds16(src, (char*)&Xl[buf][0] + sl);
    }
  };

  stage(0, 0);
  __syncthreads();
#pragma unroll
  for (int kt = 0; kt < 8; ++kt) {
    const int buf = kt & 1;
    if (kt < 7) stage(kt + 1, buf ^ 1);
#pragma unroll
    for (int kd = 0; kd < 2; ++kd) {
      bf16x8 bb[3];
#pragma unroll
      for (int j = 0; j < 3; ++j) {
        const float* p = wrow[j] + kt * 64 + kd * 32 + g * 8;
        f32x4 lo = *(const f32x4*)p;
        f32x4 hi = *(const f32x4*)(p + 4);
        uint32_t uu[4];
        uu[0] = cvt_pk_bf16(lo[0], lo[1]);
        uu[1] = cvt_pk_bf16(lo[2], lo[3]);
        uu[2] = cvt_pk_bf16(hi[0], hi[1]);
        uu[3] = cvt_pk_bf16(hi[2], hi[3]);
        bb[j] = *(bf16x8*)uu;
      }
      bf16x8 a[4];
#pragma unroll
      for (int i = 0; i < 4; ++i) {
        int Rr = wr * 64 + i * 16 + l15;
        uint32_t a32 = (uint32_t)(Rr * 256 + kd * 128 + g * 32);
        uint32_t off0 = a32 ^ ((uint32_t)(Rr & 7) << 4);
        uint32_t off1 = off0 ^ 16u;
        f32x4 lo = *(const f32x4*)((const char*)&Xl[buf][0] + off0);
        f32x4 hi = *(const f32x4*)((const char*)&Xl[buf][0] + off1);
        uint32_t uu[4];
        uu[0] = cvt_pk_bf16(lo[0], lo[1]);
        uu[1] = cvt_pk_bf16(lo[2], lo[3]);
        uu[2] = cvt_pk_bf16(hi[0], hi[1]);
        uu[3] = cvt_pk_bf16(hi[2], hi[3]);
        a[i] = *(bf16x8*)uu;
      }
#pragma unroll
      for (int i = 0; i < 4; ++i)
#pragma unroll
        for (int j = 0; j < 3; ++j)
          acc[i][j] = __builtin_amdgcn_mfma_f32_16x16x32_bf16(a[i], bb[j], acc[i][j], 0, 0, 0);
    }
    __syncthreads();
  }
#pragma unroll
  for (int i = 0; i < 4; ++i) {
    int rl2 = wr * 64 + i * 16 + g * 4;
    size_t rbase = (size_t)(R0 + rl2) * 64;
#pragma unroll
    for (int j = 0; j < 3; ++j) {
      int n = wc * 48 + j * 16 + l15;
      int sel = n >> 6, d = n & 63;
      ushort* dst = (sel == 0) ? Qw : (sel == 1) ? Kw : Vw;
      dst += rbase + d;
#pragma unroll
      for (int r = 0; r < 4; ++r) dst[(size_t)r * 64] = f2bf(acc[i][j][r]);
    }
  }
}

// ---- zrec: block (bs, nc) computes rZ[bs, n] = 1/sum_m exp(...) for n in [nc*128, +128) ----
// ---- also zeroes the odd output rows of this quarter (spare BW). Q m-tiles LDS-staged. ----
__global__ __launch_bounds__(512, 4) void zrec_kernel(
    const ushort* __restrict__ Qw, const ushort* __restrict__ Kw,
    const float* __restrict__ PEdT, float* __restrict__ rZ,
    float* __restrict__ out) {
  __shared__ char Ql[2][8192];  // 64 m-rows x 64 d bf16, swizzled
  const int tid = threadIdx.x;
  const int w = tid >> 6, lane = tid & 63, g = lane >> 4, l15 = lane & 15;
  const int bid = blockIdx.x;
  const int hi = bid >> 8, lo = bid & 255;
  const int half = lo >> 7, bs = lo & 127;
  const int nc = (hi << 1) | (half ^ hi);  // co-resident pairs (0,3),(1,2): equal work
  const int b = bs >> 4, s = bs & 15;

  // odd-row zeros for m' in [nc*128, nc*128+128)
  {
    float* ob = out + (size_t)b * 1048576;
#pragma unroll
    for (int k = 0; k < 4; ++k) {
      int jj = k * 512 + tid;
      int rowl = jj >> 4, d4 = jj & 15;
      int mrow = nc * 128 + rowl;
      float* p = ob + (size_t)(2 * (s * 512 + mrow) + 1) * 64 + d4 * 4;
      *(float4*)p = (float4){0.f, 0.f, 0.f, 0.f};
    }
  }

  const char* Qb = (const char*)(Qw + (size_t)bs * 32768);
  const char* Kb = (const char*)(Kw + (size_t)bs * 32768);
  const int nw0 = nc * 128 + w * 16;  // wave's 16 n-rows
  bf16x8 aK0, aK1;
  {
    const char* kr = Kb + (size_t)(nw0 + l15) * 128;
    aK0 = *(const bf16x8*)(kr + g * 16);
    aK1 = *(const bf16x8*)(kr + 64 + g * 16);
  }
  const int NT = 2 * (nc + 1);  // m-tiles of 64 covering m <= nc*128+127
  auto stage = [&](int mt, int buf) {
    uint32_t sl = (uint32_t)(tid * 16);
    uint32_t t = sl ^ (((sl >> 7) & 7u) << 4);  // pre-swizzled source
    uint32_t row = t >> 7, colb = t & 127u;
    gl_lds16(Qb + (size_t)(mt * 64 + row) * 128 + colb, (char*)&Ql[buf][0] + sl);
  };
  stage(0, 0);
  float z0 = 0.f, z1 = 0.f, z2 = 0.f, z3 = 0.f;
  __syncthreads();
  for (int mt = 0; mt < NT; ++mt) {
    const int buf = mt & 1;
    if (mt + 1 < NT) stage(mt + 1, buf ^ 1);
    if (mt * 64 <= nw0 + 15) {  // tiles entirely above the diagonal are all-masked
#pragma unroll
      for (int mf = 0; mf < 4; ++mf) {
        int mq = mf * 16 + l15;
        bf16x8 q0 = *(const bf16x8*)((char*)&Ql[buf][0] + swz((uint32_t)(mq * 128 + g * 16)));
        bf16x8 q1 = *(const bf16x8*)((char*)&Ql[buf][0] + swz((uint32_t)(mq * 128 + 64 + g * 16)));
        f32x4 S = (f32x4){0.f, 0.f, 0.f, 0.f};
        S = __builtin_amdgcn_mfma_f32_16x16x32_bf16(aK0, q0, S, 0, 0, 0);
        S = __builtin_amdgcn_mfma_f32_16x16x32_bf16(aK1, q1, S, 0, 0, 0);
        int m_ = mt * 64 + mq;
        f32x4 pe = *(const f32x4*)(PEdT + (size_t)m_ * 512 + nw0 + g * 4);
        int nr = nw0 + g * 4;
        if (nr + 0 >= m_) z0 += exp2f(fmaf(S[0], C_NORM_LOG2E, pe[0]));
        if (nr + 1 >= m_) z1 += exp2f(fmaf(S[1], C_NORM_LOG2E, pe[1]));
        if (nr + 2 >= m_) z2 += exp2f(fmaf(S[2], C_NORM_LOG2E, pe[2]));
        if (nr + 3 >= m_) z3 += exp2f(fmaf(S[3], C_NORM_LOG2E, pe[3]));
      }
    }
    __syncthreads();
  }
#pragma unroll
  for (int msk = 1; msk < 16; msk <<= 1) {
    z0 += __shfl_xor(z0, msk, 16);
    z1 += __shfl_xor(z1, msk, 16);
    z2 += __shfl_xor(z2, msk, 16);
    z3 += __shfl_xor(z3, msk, 16);
  }
  if (l15 == 0) {
    float* zp = rZ + (size_t)bs * 512 + nw0 + g * 4;
    zp[0] = 1.0f / z0;
    zp[1] = 1.0f / z1;
    zp[2] = 1.0f / z2;
    zp[3] = 1.0f / z3;
  }
}

// ---- attn: block (bs, ms) owns output rows m in [ms*128, +128); per wave 16 m-rows. ----
// ---- P normalized at exp time via precomputed rZ[n]; f32 acc over all n; direct out. ----
__global__ __launch_bounds__(512, 4) void attn_kernel(
    const ushort* __restrict__ Qw, const ushort* __restrict__ Kw,
    const ushort* __restrict__ Vw, const float* __restrict__ PEdT,
    const float* __restrict__ rZ, float* __restrict__ out) {
  __shared__ char Vtl[2][8192];  // V^T tile [64 d][64 n] bf16, swizzled
  __shared__ char Ptl[8][2048];  // per-wave P^T [16 m][64 n] bf16, swizzled

  const int tid = threadIdx.x;
  const int w = tid >> 6, lane = tid & 63, g = lane >> 4, l15 = lane & 15;
  const int bid = blockIdx.x;
  const int hi = bid >> 8, lo = bid & 255;
  const int half = lo >> 7, bs = lo & 127;
  const int ms = (hi << 1) | (half ^ hi);  // co-resident pairs (0,3),(1,2): 8+2 / 6+4 tiles
  const int m0w = ms * 128 + w * 16;       // wave's m base
  const size_t base = (size_t)bs * 32768;
  const char* Qb = (const char*)(Qw + base);
  const char* Kb = (const char*)(Kw + base);
  const char* Vb = (const char*)(Vw + base);
  char* Pw = &Ptl[w][0];

  // persistent Q fragment (16 m-cols)
  bf16x8 bQ0, bQ1;
  {
    const char* qr = Qb + (size_t)(m0w + l15) * 128;
    bQ0 = *(const bf16x8*)(qr + g * 16);
    bQ1 = *(const bf16x8*)(qr + 64 + g * 16);
  }

  f32x4 acc[4];
#pragma unroll
  for (int j = 0; j < 4; ++j) acc[j] = (f32x4){0.f, 0.f, 0.f, 0.f};

  const int t0 = 2 * ms, NTT = 8 - t0;  // n-tiles t0..7 (below-diagonal skipped)
  const int vrow = tid >> 3, vseg = tid & 7;
  auto scatter = [&](uint4 d4, int buf) {
    uint32_t dwv[4] = {d4.x, d4.y, d4.z, d4.w};
#pragma unroll
    for (int t = 0; t < 4; ++t) {
      int d0 = vseg * 8 + t * 2;
      *(ushort*)(&Vtl[buf][0] + swz((uint32_t)(d0 * 128 + vrow * 2))) = (ushort)(dwv[t] & 0xffffu);
      *(ushort*)(&Vtl[buf][0] + swz((uint32_t)((d0 + 1) * 128 + vrow * 2))) = (ushort)(dwv[t] >> 16);
    }
  };

  uint4 dv = *(const uint4*)(Vb + (size_t)t0 * 8192 + vrow * 128 + vseg * 16);
  scatter(dv, 0);
  if (NTT > 1) dv = *(const uint4*)(Vb + (size_t)(t0 + 1) * 8192 + vrow * 128 + vseg * 16);
  __syncthreads();

  for (int tt = 0; tt < NTT; ++tt) {
    const int t = t0 + tt, buf = tt & 1;
    if (tt + 1 < NTT) {
      scatter(dv, buf ^ 1);
      if (tt + 2 < NTT)
        dv = *(const uint4*)(Vb + (size_t)(t + 2) * 8192 + vrow * 128 + vseg * 16);
    }
    const bool wact = (m0w <= t * 64 + 63);  // diagonal-tile wave skip
    if (wact) {
      const int m_ = m0w + l15;
#pragma unroll
      for (int nf = 0; nf < 4; ++nf) {
        const char* kr = Kb + (size_t)t * 8192 + (size_t)(nf * 16 + l15) * 128;
        bf16x8 k0 = *(const bf16x8*)(kr + g * 16);
        bf16x8 k1 = *(const bf16x8*)(kr + 64 + g * 16);
        f32x4 S = (f32x4){0.f, 0.f, 0.f, 0.f};
        S = __builtin_amdgcn_mfma_f32_16x16x32_bf16(k0, bQ0, S, 0, 0, 0);
        S = __builtin_amdgcn_mfma_f32_16x16x32_bf16(k1, bQ1, S, 0, 0, 0);
        const int nb = t * 64 + nf * 16 + g * 4;
        f32x4 pe = *(const f32x4*)(PEdT + (size_t)m_ * 512 + nb);
        f32x4 rz4 = *(const f32x4*)(rZ + (size_t)bs * 512 + nb);
        float e0 = (nb + 0 >= m_) ? exp2f(fmaf(S[0], C_NORM_LOG2E, pe[0])) * rz4[0] : 0.f;
        float e1 = (nb + 1 >= m_) ? exp2f(fmaf(S[1], C_NORM_LOG2E, pe[1])) * rz4[1] : 0.f;
        float e2 = (nb + 2 >= m_) ? exp2f(fmaf(S[2], C_NORM_LOG2E, pe[2])) * rz4[2] : 0.f;
        float e3 = (nb + 3 >= m_) ? exp2f(fmaf(S[3], C_NORM_LOG2E, pe[3])) * rz4[3] : 0.f;
        uint2 u;
        u.x = cvt_pk_bf16(e0, e1);
        u.y = cvt_pk_bf16(e2, e3);
        *(uint2*)(Pw + swz((uint32_t)(l15 * 128 + nf * 32 + g * 8))) = u;
      }
#pragma unroll
      for (int kf = 0; kf < 2; ++kf) {
        bf16x8 aP = *(const bf16x8*)(Pw + swz((uint32_t)(l15 * 128 + kf * 64 + g * 16)));
#pragma unroll
        for (int df = 0; df < 4; ++df) {
          bf16x8 bV = *(const bf16x8*)(&Vtl[buf][0] +
                                       swz((uint32_t)((df * 16 + l15) * 128 + kf * 64 + g * 16)));
          acc[df] = __builtin_amdgcn_mfma_f32_16x16x32_bf16(aP, bV, acc[df], 0, 0, 0);
        }
      }
    }
    __syncthreads();
  }

  // epilogue: out[b, 2*(s*512+m), d] = acc (even rows; odd rows zeroed by zrec)
  const int b = bs >> 4, s = bs & 15;
  float* ob = out + (size_t)b * 1048576;
#pragma unroll
  for (int df = 0; df < 4; ++df)
#pragma unroll
    for (int r = 0; r < 4; ++r) {
      int m_ = m0w + g * 4 + r;
      ob[(size_t)(2 * (s * 512 + m_)) * 64 + df * 16 + l15] = acc[df][r];
    }
}

extern "C" void kernel_launch(void* const* d_in, const int* in_sizes, int n_in,
                              void* d_out, int out_size, void* d_ws, size_t ws_size,
                              hipStream_t stream) {
  const float* x  = (const float*)d_in[0];
  const float* Wk = (const float*)d_in[1];
  const float* Wq = (const float*)d_in[2];
  const float* Wv = (const float*)d_in[3];
  const float* PE = (const float*)d_in[4];
  float* out = (float*)d_out;
  char* ws = (char*)d_ws;

  ushort* Qw   = (ushort*)(ws);              // 8 MB
  ushort* Kw   = (ushort*)(ws + 8388608);    // 8 MB
  ushort* Vw   = (ushort*)(ws + 16777216);   // 8 MB
  float*  PEdT = (float*)(ws + 25165824);    // 1 MB
  float*  rZ   = (float*)(ws + 26214400);    // 256 KB

  proj_kernel<<<dim3(1024), dim3(512), 0, stream>>>(x, Wk, Wq, Wv, PE, Qw, Kw, Vw, PEdT);
  zrec_kernel<<<dim3(512), dim3(512), 0, stream>>>(Qw, Kw, PEdT, rZ, out);
  attn_kernel<<<dim3(512), dim3(512), 0, stream>>>(Qw, Kw, Vw, PEdT, rZ, out);
}

// Round 10
// 101.619 us; speedup vs baseline: 1.1521x; 1.1521x over previous
//
#include <hip/hip_runtime.h>
#include <stdint.h>

typedef __attribute__((ext_vector_type(4))) float f32x4;
typedef __attribute__((ext_vector_type(8))) short bf16x8;

#define C_NORM_LOG2E 0.18033688011112043f

// 128B-row swizzle: XOR row&7 (addr bits 7-9) into byte bits 4-6
__device__ __forceinline__ uint32_t swz(uint32_t a) { return a ^ (((a >> 7) & 7u) << 4); }

__device__ __forceinline__ uint32_t cvt_pk_bf16(float a, float b) {
  uint32_t r;
  asm("v_cvt_pk_bf16_f32 %0, %1, %2" : "=v"(r) : "v"(a), "v"(b));
  return r;
}

__device__ __forceinline__ ushort f2bf(float f) {
  uint32_t u = __float_as_uint(f);
  u += 0x7FFFu + ((u >> 16) & 1u);
  return (ushort)(u >> 16);
}

__device__ __forceinline__ void gl_lds16(const void* gp, void* lp) {
  __builtin_amdgcn_global_load_lds((const __attribute__((address_space(1))) void*)gp,
                                   (__attribute__((address_space(3))) void*)lp, 16, 0, 0);
}

// ---- pack: Wp [192][512] bf16 (Wq|Wk|Wv) and PEdT[m][n] = PE[2n][2m]*NORM*log2e ----
// PE part iterates transposed (n outer, m inner) so PE reads are lane-coalesced;
// strided PEdT writes are absorbed by L2 (1 MB, write-back).
__global__ void pack_kernel(const float* __restrict__ Wk, const float* __restrict__ Wq,
                            const float* __restrict__ Wv, const float* __restrict__ PE,
                            ushort* __restrict__ Wp, float* __restrict__ PEdT) {
  int bid = blockIdx.x;
  if (bid < 384) {
    int i = bid * 256 + threadIdx.x;  // 192*512
    int n = i >> 9, e = i & 511;
    float val = (n < 64) ? Wq[n * 512 + e]
              : (n < 128) ? Wk[(n - 64) * 512 + e]
                          : Wv[(n - 128) * 512 + e];
    Wp[i] = f2bf(val);
  } else {
    int i = (bid - 384) * 256 + threadIdx.x;  // 512*512
    int n = i >> 9, m = i & 511;              // lane-consecutive m -> coalesced PE read
    PEdT[m * 512 + n] = PE[n * 2048 + m * 2] * C_NORM_LOG2E;
  }
}

// ---------------- projection: QKV[r][d] bf16, r = (b*16+s)*512 + m, from x[b, 32m+s, :] --------
__global__ __launch_bounds__(512, 4) void proj_kernel(
    const float* __restrict__ x, const ushort* __restrict__ Wp,
    ushort* __restrict__ Qw, ushort* __restrict__ Kw, ushort* __restrict__ Vw) {
  __shared__ float Xl[2][8192];  // 2 x 32KB: 128 rows x 64 f32, swizzled (256B rows)
  const int tid = threadIdx.x;
  const int lane = tid & 63, w = tid >> 6, g = lane >> 4, l15 = lane & 15;
  const int wr = w >> 2, wc = w & 3;  // 2x4 wave grid: 64 rows x 48 cols each
  const int bid = blockIdx.x;
  const int xcd = bid & 7, idx = bid >> 3;
  const int part = idx & 3, h = idx >> 2;
  const int bs = h * 8 + xcd;
  const int m0 = part * 128;
  const int R0 = bs * 512 + m0;
  const int b = bs >> 4, s = bs & 15;
  const char* xb = (const char*)x + ((size_t)b * 8388608 + (size_t)s * 512) * 4;

  f32x4 acc[4][3];
#pragma unroll
  for (int i = 0; i < 4; ++i)
#pragma unroll
    for (int j = 0; j < 3; ++j) acc[i][j] = (f32x4){0.f, 0.f, 0.f, 0.f};

  auto stage = [&](int kt, int buf) {
#pragma unroll
    for (int j = 0; j < 4; ++j) {
      uint32_t sl = (uint32_t)(j * 8192 + tid * 16);      // linear LDS byte slot
      uint32_t t = sl ^ (((sl >> 8) & 7u) << 4);          // pre-swizzled source index
      uint32_t row = t >> 8, colb = t & 255u;
      const char* src = xb + (size_t)(m0 + row) * 65536 + (size_t)kt * 256 + colb;
      gl_lds16(src, (char*)&Xl[buf][0] + sl);
    }
  };

  stage(0, 0);
  __syncthreads();
#pragma unroll
  for (int kt = 0; kt < 8; ++kt) {
    const int buf = kt & 1;
    if (kt < 7) stage(kt + 1, buf ^ 1);
#pragma unroll
    for (int kd = 0; kd < 2; ++kd) {
      bf16x8 bb[3];
#pragma unroll
      for (int j = 0; j < 3; ++j)
        bb[j] = *(const bf16x8*)((const char*)Wp + (size_t)(wc * 48 + j * 16 + l15) * 1024 +
                                 kt * 128 + kd * 64 + g * 16);
      bf16x8 a[4];
#pragma unroll
      for (int i = 0; i < 4; ++i) {
        int Rr = wr * 64 + i * 16 + l15;
        uint32_t a32 = (uint32_t)(Rr * 256 + kd * 128 + g * 32);
        uint32_t off0 = a32 ^ ((uint32_t)(Rr & 7) << 4);
        uint32_t off1 = off0 ^ 16u;
        f32x4 lo = *(const f32x4*)((const char*)&Xl[buf][0] + off0);
        f32x4 hi = *(const f32x4*)((const char*)&Xl[buf][0] + off1);
        uint32_t uu[4];
        uu[0] = cvt_pk_bf16(lo[0], lo[1]);
        uu[1] = cvt_pk_bf16(lo[2], lo[3]);
        uu[2] = cvt_pk_bf16(hi[0], hi[1]);
        uu[3] = cvt_pk_bf16(hi[2], hi[3]);
        a[i] = *(bf16x8*)uu;
      }
#pragma unroll
      for (int i = 0; i < 4; ++i)
#pragma unroll
        for (int j = 0; j < 3; ++j)
          acc[i][j] = __builtin_amdgcn_mfma_f32_16x16x32_bf16(a[i], bb[j], acc[i][j], 0, 0, 0);
    }
    __syncthreads();
  }
#pragma unroll
  for (int i = 0; i < 4; ++i) {
    int rl2 = wr * 64 + i * 16 + g * 4;
    size_t rbase = (size_t)(R0 + rl2) * 64;
#pragma unroll
    for (int j = 0; j < 3; ++j) {
      int n = wc * 48 + j * 16 + l15;
      int sel = n >> 6, d = n & 63;
      ushort* dst = (sel == 0) ? Qw : (sel == 1) ? Kw : Vw;
      dst += rbase + d;
#pragma unroll
      for (int r = 0; r < 4; ++r) dst[(size_t)r * 64] = f2bf(acc[i][j][r]);
    }
  }
}

// ---- zrec: block (bs, nc) computes rZ[bs, n] = 1/sum_m exp(...) for n in [nc*128, +128) ----
// ---- also zeroes the odd output rows of this quarter (spare BW). Q m-tiles LDS-staged. ----
__global__ __launch_bounds__(512, 4) void zrec_kernel(
    const ushort* __restrict__ Qw, const ushort* __restrict__ Kw,
    const float* __restrict__ PEdT, float* __restrict__ rZ,
    float* __restrict__ out) {
  __shared__ char Ql[2][8192];  // 64 m-rows x 64 d bf16, swizzled
  const int tid = threadIdx.x;
  const int w = tid >> 6, lane = tid & 63, g = lane >> 4, l15 = lane & 15;
  const int bid = blockIdx.x;
  const int hi = bid >> 8, lo = bid & 255;
  const int half = lo >> 7, bs = lo & 127;
  const int nc = (hi << 1) | (half ^ hi);  // co-resident pairs (0,3),(1,2): equal work
  const int b = bs >> 4, s = bs & 15;

  // odd-row zeros for m' in [nc*128, nc*128+128)
  {
    float* ob = out + (size_t)b * 1048576;
#pragma unroll
    for (int k = 0; k < 4; ++k) {
      int jj = k * 512 + tid;
      int rowl = jj >> 4, d4 = jj & 15;
      int mrow = nc * 128 + rowl;
      float* p = ob + (size_t)(2 * (s * 512 + mrow) + 1) * 64 + d4 * 4;
      *(float4*)p = (float4){0.f, 0.f, 0.f, 0.f};
    }
  }

  const char* Qb = (const char*)(Qw + (size_t)bs * 32768);
  const char* Kb = (const char*)(Kw + (size_t)bs * 32768);
  const int nw0 = nc * 128 + w * 16;  // wave's 16 n-rows
  bf16x8 aK0, aK1;
  {
    const char* kr = Kb + (size_t)(nw0 + l15) * 128;
    aK0 = *(const bf16x8*)(kr + g * 16);
    aK1 = *(const bf16x8*)(kr + 64 + g * 16);
  }
  const int NT = 2 * (nc + 1);  // m-tiles of 64 covering m <= nc*128+127
  auto stage = [&](int mt, int buf) {
    uint32_t sl = (uint32_t)(tid * 16);
    uint32_t t = sl ^ (((sl >> 7) & 7u) << 4);  // pre-swizzled source
    uint32_t row = t >> 7, colb = t & 127u;
    gl_lds16(Qb + (size_t)(mt * 64 + row) * 128 + colb, (char*)&Ql[buf][0] + sl);
  };
  stage(0, 0);
  float z0 = 0.f, z1 = 0.f, z2 = 0.f, z3 = 0.f;
  __syncthreads();
  for (int mt = 0; mt < NT; ++mt) {
    const int buf = mt & 1;
    if (mt + 1 < NT) stage(mt + 1, buf ^ 1);
    if (mt * 64 <= nw0 + 15) {  // tiles entirely above the diagonal are all-masked
#pragma unroll
      for (int mf = 0; mf < 4; ++mf) {
        int mq = mf * 16 + l15;
        bf16x8 q0 = *(const bf16x8*)((char*)&Ql[buf][0] + swz((uint32_t)(mq * 128 + g * 16)));
        bf16x8 q1 = *(const bf16x8*)((char*)&Ql[buf][0] + swz((uint32_t)(mq * 128 + 64 + g * 16)));
        f32x4 S = (f32x4){0.f, 0.f, 0.f, 0.f};
        S = __builtin_amdgcn_mfma_f32_16x16x32_bf16(aK0, q0, S, 0, 0, 0);
        S = __builtin_amdgcn_mfma_f32_16x16x32_bf16(aK1, q1, S, 0, 0, 0);
        int m_ = mt * 64 + mq;
        f32x4 pe = *(const f32x4*)(PEdT + (size_t)m_ * 512 + nw0 + g * 4);
        int nr = nw0 + g * 4;
        if (nr + 0 >= m_) z0 += exp2f(fmaf(S[0], C_NORM_LOG2E, pe[0]));
        if (nr + 1 >= m_) z1 += exp2f(fmaf(S[1], C_NORM_LOG2E, pe[1]));
        if (nr + 2 >= m_) z2 += exp2f(fmaf(S[2], C_NORM_LOG2E, pe[2]));
        if (nr + 3 >= m_) z3 += exp2f(fmaf(S[3], C_NORM_LOG2E, pe[3]));
      }
    }
    __syncthreads();
  }
#pragma unroll
  for (int msk = 1; msk < 16; msk <<= 1) {
    z0 += __shfl_xor(z0, msk, 16);
    z1 += __shfl_xor(z1, msk, 16);
    z2 += __shfl_xor(z2, msk, 16);
    z3 += __shfl_xor(z3, msk, 16);
  }
  if (l15 == 0) {
    float* zp = rZ + (size_t)bs * 512 + nw0 + g * 4;
    zp[0] = 1.0f / z0;
    zp[1] = 1.0f / z1;
    zp[2] = 1.0f / z2;
    zp[3] = 1.0f / z3;
  }
}

// ---- attn: block (bs, ms) owns output rows m in [ms*128, +128); per wave 16 m-rows. ----
// ---- P normalized at exp time via precomputed rZ[n]; f32 acc over all n; direct out. ----
__global__ __launch_bounds__(512, 4) void attn_kernel(
    const ushort* __restrict__ Qw, const ushort* __restrict__ Kw,
    const ushort* __restrict__ Vw, const float* __restrict__ PEdT,
    const float* __restrict__ rZ, float* __restrict__ out) {
  __shared__ char Vtl[2][8192];  // V^T tile [64 d][64 n] bf16, swizzled
  __shared__ char Ptl[8][2048];  // per-wave P^T [16 m][64 n] bf16, swizzled

  const int tid = threadIdx.x;
  const int w = tid >> 6, lane = tid & 63, g = lane >> 4, l15 = lane & 15;
  const int bid = blockIdx.x;
  const int hi = bid >> 8, lo = bid & 255;
  const int half = lo >> 7, bs = lo & 127;
  const int ms = (hi << 1) | (half ^ hi);  // co-resident pairs (0,3),(1,2): 8+2 / 6+4 tiles
  const int m0w = ms * 128 + w * 16;       // wave's m base
  const size_t base = (size_t)bs * 32768;
  const char* Qb = (const char*)(Qw + base);
  const char* Kb = (const char*)(Kw + base);
  const char* Vb = (const char*)(Vw + base);
  char* Pw = &Ptl[w][0];

  // persistent Q fragment (16 m-cols)
  bf16x8 bQ0, bQ1;
  {
    const char* qr = Qb + (size_t)(m0w + l15) * 128;
    bQ0 = *(const bf16x8*)(qr + g * 16);
    bQ1 = *(const bf16x8*)(qr + 64 + g * 16);
  }

  f32x4 acc[4];
#pragma unroll
  for (int j = 0; j < 4; ++j) acc[j] = (f32x4){0.f, 0.f, 0.f, 0.f};

  const int t0 = 2 * ms, NTT = 8 - t0;  // n-tiles t0..7 (below-diagonal skipped)
  const int vrow = tid >> 3, vseg = tid & 7;
  auto scatter = [&](uint4 d4, int buf) {
    uint32_t dwv[4] = {d4.x, d4.y, d4.z, d4.w};
#pragma unroll
    for (int t = 0; t < 4; ++t) {
      int d0 = vseg * 8 + t * 2;
      *(ushort*)(&Vtl[buf][0] + swz((uint32_t)(d0 * 128 + vrow * 2))) = (ushort)(dwv[t] & 0xffffu);
      *(ushort*)(&Vtl[buf][0] + swz((uint32_t)((d0 + 1) * 128 + vrow * 2))) = (ushort)(dwv[t] >> 16);
    }
  };

  uint4 dv = *(const uint4*)(Vb + (size_t)t0 * 8192 + vrow * 128 + vseg * 16);
  scatter(dv, 0);
  if (NTT > 1) dv = *(const uint4*)(Vb + (size_t)(t0 + 1) * 8192 + vrow * 128 + vseg * 16);
  __syncthreads();

  for (int tt = 0; tt < NTT; ++tt) {
    const int t = t0 + tt, buf = tt & 1;
    if (tt + 1 < NTT) {
      scatter(dv, buf ^ 1);
      if (tt + 2 < NTT)
        dv = *(const uint4*)(Vb + (size_t)(t + 2) * 8192 + vrow * 128 + vseg * 16);
    }
    const bool wact = (m0w <= t * 64 + 63);  // diagonal-tile wave skip
    if (wact) {
      const int m_ = m0w + l15;
#pragma unroll
      for (int nf = 0; nf < 4; ++nf) {
        const char* kr = Kb + (size_t)t * 8192 + (size_t)(nf * 16 + l15) * 128;
        bf16x8 k0 = *(const bf16x8*)(kr + g * 16);
        bf16x8 k1 = *(const bf16x8*)(kr + 64 + g * 16);
        f32x4 S = (f32x4){0.f, 0.f, 0.f, 0.f};
        S = __builtin_amdgcn_mfma_f32_16x16x32_bf16(k0, bQ0, S, 0, 0, 0);
        S = __builtin_amdgcn_mfma_f32_16x16x32_bf16(k1, bQ1, S, 0, 0, 0);
        const int nb = t * 64 + nf * 16 + g * 4;
        f32x4 pe = *(const f32x4*)(PEdT + (size_t)m_ * 512 + nb);
        f32x4 rz4 = *(const f32x4*)(rZ + (size_t)bs * 512 + nb);
        float e0 = (nb + 0 >= m_) ? exp2f(fmaf(S[0], C_NORM_LOG2E, pe[0])) * rz4[0] : 0.f;
        float e1 = (nb + 1 >= m_) ? exp2f(fmaf(S[1], C_NORM_LOG2E, pe[1])) * rz4[1] : 0.f;
        float e2 = (nb + 2 >= m_) ? exp2f(fmaf(S[2], C_NORM_LOG2E, pe[2])) * rz4[2] : 0.f;
        float e3 = (nb + 3 >= m_) ? exp2f(fmaf(S[3], C_NORM_LOG2E, pe[3])) * rz4[3] : 0.f;
        uint2 u;
        u.x = cvt_pk_bf16(e0, e1);
        u.y = cvt_pk_bf16(e2, e3);
        *(uint2*)(Pw + swz((uint32_t)(l15 * 128 + nf * 32 + g * 8))) = u;
      }
#pragma unroll
      for (int kf = 0; kf < 2; ++kf) {
        bf16x8 aP = *(const bf16x8*)(Pw + swz((uint32_t)(l15 * 128 + kf * 64 + g * 16)));
#pragma unroll
        for (int df = 0; df < 4; ++df) {
          bf16x8 bV = *(const bf16x8*)(&Vtl[buf][0] +
                                       swz((uint32_t)((df * 16 + l15) * 128 + kf * 64 + g * 16)));
          acc[df] = __builtin_amdgcn_mfma_f32_16x16x32_bf16(aP, bV, acc[df], 0, 0, 0);
        }
      }
    }
    __syncthreads();
  }

  // epilogue: out[b, 2*(s*512+m), d] = acc (even rows; odd rows zeroed by zrec)
  const int b = bs >> 4, s = bs & 15;
  float* ob = out + (size_t)b * 1048576;
#pragma unroll
  for (int df = 0; df < 4; ++df)
#pragma unroll
    for (int r = 0; r < 4; ++r) {
      int m_ = m0w + g * 4 + r;
      ob[(size_t)(2 * (s * 512 + m_)) * 64 + df * 16 + l15] = acc[df][r];
    }
}

extern "C" void kernel_launch(void* const* d_in, const int* in_sizes, int n_in,
                              void* d_out, int out_size, void* d_ws, size_t ws_size,
                              hipStream_t stream) {
  const float* x  = (const float*)d_in[0];
  const float* Wk = (const float*)d_in[1];
  const float* Wq = (const float*)d_in[2];
  const float* Wv = (const float*)d_in[3];
  const float* PE = (const float*)d_in[4];
  float* out = (float*)d_out;
  char* ws = (char*)d_ws;

  ushort* Qw   = (ushort*)(ws);              // 8 MB
  ushort* Kw   = (ushort*)(ws + 8388608);    // 8 MB
  ushort* Vw   = (ushort*)(ws + 16777216);   // 8 MB
  ushort* Wp   = (ushort*)(ws + 25165824);   // 192 KB
  float*  PEdT = (float*)(ws + 25362432);    // 1 MB
  float*  rZ   = (float*)(ws + 26411008);    // 256 KB

  pack_kernel<<<dim3(1408), dim3(256), 0, stream>>>(Wk, Wq, Wv, PE, Wp, PEdT);
  proj_kernel<<<dim3(512), dim3(512), 0, stream>>>(x, Wp, Qw, Kw, Vw);
  zrec_kernel<<<dim3(512), dim3(512), 0, stream>>>(Qw, Kw, PEdT, rZ, out);
  attn_kernel<<<dim3(512), dim3(512), 0, stream>>>(Qw, Kw, Vw, PEdT, rZ, out);
}